// Round 1
// baseline (661.596 us; speedup 1.0000x reference)
//
#include <hip/hip_runtime.h>

// ---------------------------------------------------------------------------
// TopK sparse attention, MI355X (gfx950)
// B=4 L=1024 E=1024 H=16 DH=64 TOPK=32
//
// Numerics (validated r3-r5, absmax 0.0176 < 0.0206): reference top-k is
// fp32-noisy; keys within btau=1.5e-5 of the rank-32/33 midpoint get
// ensemble-blended weight (32-A)/m. Selection needs logit err << btau.
// Round-6: all 4 GEMMs use fp16 3-slot split [h,l,h]x[h,h,l] (hh+lh+hl,
// residual ~2^-24), K=3072, W prescaled x32 so l-terms stay fp16-normal
// (worst-case denormal-flush err ~2.5e-6 scaled << btau). Candidate re-dot
// fp32 q,k / fp64 accum as before.
// Round-7: kill the attn selection latency chains. 64-lane bitonic sort
// (42 serial ds_bpermute, ~1.5k cyc/row) -> exact 32-bit threshold search
// for the 32nd largest (scalar chain, no LDS) + masked reduce for the 33rd
// + ballot-prefix ds_permute compaction. Gather/broadcast shuffles with
// uniform lane index -> v_readlane (VALU, no LDS pipe). Band/blend
// semantics identical (e31/e32v are the same float values as the sorted
// version; only gather summation order changes -> fp noise only).
// ---------------------------------------------------------------------------

typedef short v8s __attribute__((ext_vector_type(8)));
typedef _Float16 v8h __attribute__((ext_vector_type(8)));
typedef float v4f __attribute__((ext_vector_type(4)));

#define B_ 4
#define L_ 1024
#define E_ 1024
#define H_ 16
#define DH_ 64
#define M_ 4096   // B*L

__device__ __forceinline__ unsigned short f2bf_u(float f) {
    unsigned u = __float_as_uint(f);
    unsigned r = u + 0x7FFFu + ((u >> 16) & 1u);   // RNE
    return (unsigned short)(r >> 16);
}
__device__ __forceinline__ unsigned short f2h_u(float f) {
    _Float16 h = (_Float16)f;
    union { _Float16 h; unsigned short u; } c; c.h = h; return c.u;
}
__device__ __forceinline__ float h2f_u(unsigned short u) {
    union { _Float16 h; unsigned short u; } c; c.u = u; return (float)c.h;
}
__device__ __forceinline__ unsigned f2key(float f) {
    unsigned u = __float_as_uint(f);
    u = ((int)u < 0) ? ~u : (u | 0x80000000u);
    return u & 0xFFFFFFF0u;
}
__device__ __forceinline__ unsigned f2keyfull(float f) {   // no low-bit mask
    unsigned u = __float_as_uint(f);
    return ((int)u < 0) ? ~u : (u | 0x80000000u);
}
__device__ __forceinline__ float key2f(unsigned k) {
    unsigned u = (k & 0x80000000u) ? (k & 0x7FFFFFFFu) : ~k;
    return __uint_as_float(u);
}
__device__ __forceinline__ float rl_f(float v, int l) {    // uniform-lane broadcast
    return __uint_as_float((unsigned)__builtin_amdgcn_readlane(__float_as_int(v), l));
}
__device__ __forceinline__ int rl_i(int v, int l) {
    return __builtin_amdgcn_readlane(v, l);
}
__device__ __forceinline__ void gload_lds16(const unsigned short* g, unsigned short* l) {
    __builtin_amdgcn_global_load_lds(
        (const __attribute__((address_space(1))) void*)g,
        (__attribute__((address_space(3))) void*)l, 16, 0, 0);
}

// ---------------------------------------------------------------------------
// fp16 3-slot split, 8 elements/thread.
// A (isB=0): [h,l,h]   B (isB=1): [h,h,l]   -> GEMM computes hh+lh+hl.
// prescale: 1 for X, 32 for W (keeps l-terms fp16-normal; /32 in epilogue).
// ---------------------------------------------------------------------------
__global__ __launch_bounds__(256) void splitH_kernel(
    const float* __restrict__ x, unsigned short* __restrict__ y,
    int n8, int isB, float prescale)
{
    int i = blockIdx.x * 256 + threadIdx.x;
    if (i >= n8) return;
    float4 v0 = *(const float4*)(x + 8*(size_t)i);
    float4 v1 = *(const float4*)(x + 8*(size_t)i + 4);
    float f[8] = {v0.x, v0.y, v0.z, v0.w, v1.x, v1.y, v1.z, v1.w};
    unsigned short o[24];
#pragma unroll
    for (int c = 0; c < 8; ++c) {
        float fv = f[c] * prescale;
        unsigned short h = f2h_u(fv);
        float r = fv - h2f_u(h);
        unsigned short l = f2h_u(r);
        int b = 3*c;
        if (!isB) { o[b] = h; o[b+1] = l; o[b+2] = h; }
        else      { o[b] = h; o[b+1] = h; o[b+2] = l; }
    }
    uint4* dst = (uint4*)(y + 24*(size_t)i);
    const unsigned* ou = (const unsigned*)o;
    dst[0] = make_uint4(ou[0], ou[1], ou[2], ou[3]);
    dst[1] = make_uint4(ou[4], ou[5], ou[6], ou[7]);
    dst[2] = make_uint4(ou[8], ou[9], ou[10], ou[11]);
}

// ---------------------------------------------------------------------------
// fp16 NT GEMM, 128x64 C-tile, global_load_lds(16B) staging.
// C[m,n] = (sum_k A[m,k]*Bw[n,k]) * (1/32) + bias[n], then *scale.
// M=4096, N=1024, K2=3072. grid (16 n-tiles, 32 m-tiles) = 512 blocks (2/CU).
// 4 waves, each 32 rows x 64 cols (2x4 MFMA tiles, 16x16x32 f16).
// mode 0: outF[m*1024+n]; mode 1: outF[bh-layout]; mode 2: +outB bf16.
// ---------------------------------------------------------------------------
__global__ __launch_bounds__(256) void gemm_f16(
    const unsigned short* __restrict__ A,
    const unsigned short* __restrict__ Bw,
    const float* __restrict__ bias,
    int K2, int mode, float scale,
    float* __restrict__ outF,
    unsigned short* __restrict__ outB)
{
    __shared__ __align__(16) unsigned short As[128*64];
    __shared__ __align__(16) unsigned short Bs[64*64];
    const int t    = threadIdx.x;
    const int lane = t & 63;
    const int w    = t >> 6;
    const int quad = lane >> 4;
    const int l16  = lane & 15;
    const int n0   = blockIdx.x * 64;
    const int m0   = blockIdx.y * 128;
    const int wr   = w * 32;

    v4f acc[2][4];
#pragma unroll
    for (int i = 0; i < 2; ++i)
#pragma unroll
        for (int j = 0; j < 4; ++j) acc[i][j] = (v4f){0.f,0.f,0.f,0.f};

    const unsigned short* Ap = A  + (size_t)(m0 + (t >> 3)) * K2 + (t & 7)*8;
    const unsigned short* Bp = Bw + (size_t)(n0 + (t >> 3)) * K2 + (t & 7)*8;
    unsigned short* ldsA = &As[t*8];   // lane-linear 16B slots
    unsigned short* ldsB = &Bs[t*8];
    const size_t cstep = (size_t)32 * K2;

    for (int k0 = 0; k0 < K2; k0 += 64) {
        __syncthreads();               // readers done with LDS
#pragma unroll
        for (int c = 0; c < 4; ++c) gload_lds16(Ap + c*cstep + k0, ldsA + c*2048);
#pragma unroll
        for (int c = 0; c < 2; ++c) gload_lds16(Bp + c*cstep + k0, ldsB + c*2048);
        __syncthreads();               // vmcnt(0) drained before barrier
#pragma unroll
        for (int ks = 0; ks < 2; ++ks) {
            v8h af[2], bf[4];
#pragma unroll
            for (int mt = 0; mt < 2; ++mt)
                af[mt] = *(const v8h*)&As[(wr + mt*16 + l16)*64 + ks*32 + quad*8];
#pragma unroll
            for (int nt = 0; nt < 4; ++nt)
                bf[nt] = *(const v8h*)&Bs[(nt*16 + l16)*64 + ks*32 + quad*8];
#pragma unroll
            for (int mt = 0; mt < 2; ++mt)
#pragma unroll
                for (int nt = 0; nt < 4; ++nt)
                    acc[mt][nt] = __builtin_amdgcn_mfma_f32_16x16x32_f16(
                        af[mt], bf[nt], acc[mt][nt], 0, 0, 0);
        }
    }

#pragma unroll
    for (int nt = 0; nt < 4; ++nt) {
        int n = n0 + nt*16 + l16;
        float bb = bias[n];
#pragma unroll
        for (int mt = 0; mt < 2; ++mt) {
#pragma unroll
            for (int r = 0; r < 4; ++r) {
                int m = m0 + wr + mt*16 + quad*4 + r;
                float val = (acc[mt][nt][r] * 0.03125f + bb) * scale;
                if (mode == 0) {
                    outF[(size_t)m * 1024 + n] = val;
                } else {
                    int b = m >> 10, l = m & 1023;
                    int h = n >> 6,  d = n & 63;
                    size_t oidx = (((size_t)(b*16 + h)) * 1024 + l) * 64 + d;
                    outF[oidx] = val;
                    if (mode == 2) outB[oidx] = f2bf_u(val);
                }
            }
        }
    }
}

// ---------------------------------------------------------------------------
// Attention: one block = (b,h, 8 query rows), XCD-swizzled, grid 8192.
// Coarse S: bf16 MFMA, direct global B-frags. Counts via ballot+popcount
// (wave-uniform, no shuffle chains). Re-dot fp32 q,k / fp64 accum (2-way
// ILP). Round-7 selection: exact 32-bit bitwise threshold search for the
// 32nd-largest re-dotted logit (scalar chain, no LDS traffic), masked
// shuffle-reduce for the 33rd, ambiguity-band blended softmax
// (btau=1.5e-5), ballot-prefix ds_permute compaction, readlane-driven
// 4-way unrolled V gather.
// ---------------------------------------------------------------------------
__global__ __launch_bounds__(256, 8) void attn_kernel(
    const float* __restrict__ qf,           // [64][1024][64] fp32 (scaled 1/8)
    const unsigned short* __restrict__ qb,  // bf16 of qf
    const float* __restrict__ kf,
    const unsigned short* __restrict__ kb,
    const float* __restrict__ vf,           // fp32 v, bh-layout
    float* __restrict__ ao)                 // [4096][1024]
{
    __shared__ __align__(16) float qfs[8*68];
    __shared__ __align__(16) unsigned short qbs[8*72];
    __shared__ __align__(16) float sbuf[2][8*68];
    __shared__ unsigned cand[4*64];

    const int t    = threadIdx.x;
    const int lane = t & 63;
    const int w    = t >> 6;
    const int quad = lane >> 4;
    const int l16  = lane & 15;

    // XCD swizzle: xcd = blk%8 owns bh in [xcd*8, xcd*8+8)
    const int blk = blockIdx.x;
    const int jj  = blk >> 3;               // 0..1023
    const int bh  = (blk & 7) * 8 + (jj >> 7);
    const int qt  = jj & 127;
    const int l0  = qt * 8;
    const size_t kvB = (size_t)bh * 1024;

    { // stage 8 q rows (fp32 + bf16)
        if (t < 128) {
            int row = t >> 4, c4 = (t & 15) * 4;
            *(float4*)&qfs[row*68 + c4] = *(const float4*)&qf[(kvB + l0 + row)*64 + c4];
        }
        if (t < 64) {
            int r2 = t >> 3, cc = t & 7;
            *(uint4*)&qbs[r2*72 + cc*8] = *(const uint4*)&qb[(kvB + l0 + r2)*64 + cc*8];
        }
    }
    __syncthreads();
    v8s afr[2];
#pragma unroll
    for (int ks = 0; ks < 2; ++ks)
        afr[ks] = *(const v8s*)&qbs[(l16 & 7)*72 + ks*32 + quad*8];

    unsigned skey[2][16];

    // coarse pass: wave w covers k-rows w*16+l16 within each 64-row k-tile
    const unsigned short* kbase = kb + (kvB + w*16 + l16) * 64 + quad*8;
    v8s nb0 = *(const v8s*)(kbase);
    v8s nb1 = *(const v8s*)(kbase + 32);
#pragma unroll
    for (int kt = 0; kt < 16; ++kt) {
        v8s b0 = nb0, b1 = nb1;
        if (kt < 15) {
            nb0 = *(const v8s*)(kbase + (kt+1)*4096);
            nb1 = *(const v8s*)(kbase + (kt+1)*4096 + 32);
        }
        v4f acc = (v4f){0.f,0.f,0.f,0.f};
        acc = __builtin_amdgcn_mfma_f32_16x16x32_bf16(afr[0], b0, acc, 0, 0, 0);
        acc = __builtin_amdgcn_mfma_f32_16x16x32_bf16(afr[1], b1, acc, 0, 0, 0);
        if (quad < 2) {            // rows 8..15 duplicate 0..7
#pragma unroll
            for (int r = 0; r < 4; ++r)
                sbuf[kt & 1][(quad*4 + r)*68 + w*16 + l16] = acc[r];
        }
        __syncthreads();
#pragma unroll
        for (int rr = 0; rr < 2; ++rr) {
            float sv = sbuf[kt & 1][(w*2 + rr)*68 + lane];
            unsigned u = __float_as_uint(sv);
            u = ((int)u < 0) ? ~u : (u | 0x80000000u);
            skey[rr][kt] = (u & 0xFFFFFFF0u) | (unsigned)kt;  // idx in low bits
        }
    }

#pragma unroll
    for (int rr = 0; rr < 2; ++rr) {
        const int qrow = w*2 + rr;

        // --- row max (shuffle reduce, once) ---
        unsigned kmax = 0;
#pragma unroll
        for (int kt = 0; kt < 16; ++kt) kmax = max(kmax, skey[rr][kt]);
#pragma unroll
        for (int off = 32; off; off >>= 1)
            kmax = max(kmax, (unsigned)__shfl_xor((int)kmax, off));
        float fm = key2f(kmax);

        // --- threshold search, counts via ballot+popcount (wave-uniform) ---
        unsigned tau = 0; bool ok = false;
        if (fm > 0.f) {
            float lof = 0.28f * fm, hif = 0.88f * fm;
            for (int it = 0; it < 12; ++it) {
                float midf = 0.5f * (lof + hif);
                unsigned tk = f2key(midf);
                int c = 0;
#pragma unroll
                for (int kt = 0; kt < 16; ++kt)
                    c += (int)__popcll(__ballot(skey[rr][kt] >= tk));
                tau = tk;
                if (c <= 64 && c >= 36) { ok = true; break; }
                if (c > 64) lof = midf; else hif = midf;
            }
        }
        if (!ok) { // full-range u32 fallback (guaranteed window)
            unsigned lo = 0u, hi = 0xFFFFFFFFu;
            for (int it = 0; ; ++it) {
                unsigned mid = lo + ((hi - lo) >> 1);
                int c = 0;
#pragma unroll
                for (int kt = 0; kt < 16; ++kt)
                    c += (int)__popcll(__ballot(skey[rr][kt] >= mid));
                tau = mid;
                if (it >= 33 || (c <= 64 && c >= 36)) break;
                if (c > 64) lo = mid + 1; else hi = mid - 1;
            }
        }

        // --- compact candidate indices ---
        int base = 0;
#pragma unroll
        for (int kt = 0; kt < 16; ++kt) {
            bool f = skey[rr][kt] >= tau;
            unsigned long long mk = __ballot(f);
            if (f) {
                int pos = base + (int)__popcll(mk & ((1ull << lane) - 1ull));
                if (pos < 64) cand[w*64 + pos] = (unsigned)(kt*64 + lane);
            }
            base += (int)__popcll(mk);
        }
        int cnum = base > 64 ? 64 : base;

        // --- re-dot: fp32 q,k, fp64 accumulate, 2-way ILP ---
        int cj = 0x3FFFFFFF;
        float ef = -INFINITY;
        if (lane < cnum) {
            cj = (int)cand[w*64 + lane];
            const float* kr = kf + (kvB + cj) * 64;
            double s0 = 0.0, s1 = 0.0;
#pragma unroll
            for (int d4 = 0; d4 < 16; d4 += 2) {
                float4 qa = *(const float4*)&qfs[qrow*68 + d4*4];
                float4 ka = *(const float4*)&kr[d4*4];
                float4 qb2 = *(const float4*)&qfs[qrow*68 + d4*4 + 4];
                float4 kb2 = *(const float4*)&kr[d4*4 + 4];
                s0 += (double)qa.x * ka.x; s0 += (double)qa.y * ka.y;
                s0 += (double)qa.z * ka.z; s0 += (double)qa.w * ka.w;
                s1 += (double)qb2.x * kb2.x; s1 += (double)qb2.y * kb2.y;
                s1 += (double)qb2.z * kb2.z; s1 += (double)qb2.w * kb2.w;
            }
            ef = (float)(s0 + s1);
        }

        // --- exact 32nd-largest via bitwise threshold search (no LDS) ---
        // T = max{ t : count(uf >= t) >= 32 } == sortable key of v32.
        const unsigned uf = f2keyfull(ef);
        unsigned T = 0u;
#pragma unroll
        for (int b = 31; b >= 0; --b) {
            unsigned cndt = T | (1u << b);
            int c = (int)__popcll(__ballot(uf >= cndt));
            if (c >= 32) T = cndt;            // c uniform -> s_cselect
        }
        float e31 = key2f(T);                  // 32nd largest (exact float)
        int c_ge = (int)__popcll(__ballot(uf >= T));

        // --- 33rd largest + row max (two interleaved reduce chains) ---
        float mx = ef;
        float tm = (uf < T) ? ef : -INFINITY;
#pragma unroll
        for (int off = 32; off; off >>= 1) {
            mx = fmaxf(mx, __shfl_xor(mx, off));
            tm = fmaxf(tm, __shfl_xor(tm, off));
        }
        float e32v = (c_ge >= 33) ? e31 : tm;  // duplicates at rank 32/33

        // --- ambiguity-band blended softmax (validated, btau=1.5e-5) ---
        float cmid = 0.5f * (e31 + e32v);
        const float btau = 1.5e-5f;
        bool certain = (ef > cmid + btau);
        bool band    = (fabsf(ef - cmid) <= btau);
        int A = (int)__popcll(__ballot(certain));
        int m = (int)__popcll(__ballot(band));
        float wgt = band ? ((float)(32 - A) / (float)m) : (certain ? 1.f : 0.f);

        float p = wgt * __expf(ef - mx);
        float Z = p;
#pragma unroll
        for (int off = 32; off; off >>= 1) Z += __shfl_xor(Z, off);

        // --- compact wgt>0 lanes to a prefix (full-exec permutation push) ---
        bool sel = (wgt > 0.f);
        unsigned long long mk = __ballot(sel);
        int nnz = (int)__popcll(mk);
        unsigned long long lt = (1ull << lane) - 1ull;
        int pos = sel ? (int)__popcll(mk & lt)
                      : nnz + (int)__popcll(~mk & lt);
        float pc = __uint_as_float((unsigned)__builtin_amdgcn_ds_permute(
                       pos << 2, __float_as_int(p)));
        int   cc = __builtin_amdgcn_ds_permute(pos << 2, cj);

        // --- gather V: readlane broadcasts, 4 independent chains ---
        const float* vbase = vf + kvB * 64 + lane;
        float o0 = 0.f, o1 = 0.f, o2 = 0.f, o3 = 0.f;
        int tt = 0;
        for (; tt + 3 < nnz; tt += 4) {
            float pa = rl_f(pc, tt),   pb = rl_f(pc, tt+1);
            float pcc = rl_f(pc, tt+2), pd = rl_f(pc, tt+3);
            int ia = rl_i(cc, tt),   ib = rl_i(cc, tt+1);
            int ic = rl_i(cc, tt+2), id = rl_i(cc, tt+3);
            o0 += pa  * vbase[ia * 64];
            o1 += pb  * vbase[ib * 64];
            o2 += pcc * vbase[ic * 64];
            o3 += pd  * vbase[id * 64];
        }
        for (; tt < nnz; ++tt) {
            float pt  = rl_f(pc, tt);
            int   it2 = rl_i(cc, tt);
            o0 += pt * vbase[it2 * 64];
        }
        float o = (o0 + o1) + (o2 + o3);
        int lq = l0 + qrow;
        ao[((size_t)(bh >> 4) * 1024 + lq) * 1024 + (bh & 15) * 64 + lane] = o / Z;
    }
}

// ---------------------------------------------------------------------------
extern "C" void kernel_launch(void* const* d_in, const int* in_sizes, int n_in,
                              void* d_out, int out_size, void* d_ws, size_t ws_size,
                              hipStream_t stream)
{
    const float* Q  = (const float*)d_in[0];
    const float* K  = (const float*)d_in[1];
    const float* V  = (const float*)d_in[2];
    const float* Wq = (const float*)d_in[3];
    const float* bq = (const float*)d_in[4];
    const float* Wk = (const float*)d_in[5];
    const float* bk = (const float*)d_in[6];
    const float* Wv = (const float*)d_in[7];
    const float* bv = (const float*)d_in[8];
    const float* Wo = (const float*)d_in[9];
    const float* bo = (const float*)d_in[10];
    float* out = (float*)d_out;

    // workspace layout (bytes)
    const size_t oX3 = 0;            // 4096*3072*2 = 25165824
    const size_t oW3 = 25165824;     // 1024*3072*2 = 6291456
    const size_t oQF = 31457280;     // 16777216
    const size_t oKF = 48234496;     // 16777216
    const size_t oVF = 65011712;     // 16777216
    const size_t oQB = 81788928;     // 8388608
    const size_t oKB = 90177536;     // 8388608
    const size_t oAO = 98566144;     // 16777216 -> end 115343360
    if (ws_size < 115343360) return;

    char* ws = (char*)d_ws;
    unsigned short* X3 = (unsigned short*)(ws + oX3);
    unsigned short* W3 = (unsigned short*)(ws + oW3);
    float* qf = (float*)(ws + oQF);
    float* kf = (float*)(ws + oKF);
    float* vf = (float*)(ws + oVF);
    unsigned short* qb = (unsigned short*)(ws + oQB);
    unsigned short* kb = (unsigned short*)(ws + oKB);
    float* ao = (float*)(ws + oAO);

    const int nX8 = M_ * E_ / 8;     // 524288
    const int nW8 = E_ * E_ / 8;     // 131072
    dim3 blk(256);
    dim3 gG(16, 32);                 // (n-tiles 64, m-tiles 128)
    dim3 gX(nX8 / 256), gW(nW8 / 256);

    // Q path (fold 1/sqrt(DH)=0.125 into stored q)
    splitH_kernel<<<gX, blk, 0, stream>>>(Q, X3, nX8, 0, 1.0f);
    splitH_kernel<<<gW, blk, 0, stream>>>(Wq, W3, nW8, 1, 32.0f);
    gemm_f16<<<gG, blk, 0, stream>>>(X3, W3, bq, 3072, 2, 0.125f, qf, qb);
    // K path
    splitH_kernel<<<gX, blk, 0, stream>>>(K, X3, nX8, 0, 1.0f);
    splitH_kernel<<<gW, blk, 0, stream>>>(Wk, W3, nW8, 1, 32.0f);
    gemm_f16<<<gG, blk, 0, stream>>>(X3, W3, bk, 3072, 2, 1.0f, kf, kb);
    // V path
    splitH_kernel<<<gX, blk, 0, stream>>>(V, X3, nX8, 0, 1.0f);
    splitH_kernel<<<gW, blk, 0, stream>>>(Wv, W3, nW8, 1, 32.0f);
    gemm_f16<<<gG, blk, 0, stream>>>(X3, W3, bv, 3072, 1, 1.0f, vf, nullptr);
    // attention (8 rows/block)
    attn_kernel<<<dim3(8192), blk, 0, stream>>>(qf, qb, kf, kb, vf, ao);
    // output projection
    splitH_kernel<<<gX, blk, 0, stream>>>(ao, X3, nX8, 0, 1.0f);
    splitH_kernel<<<gW, blk, 0, stream>>>(Wo, W3, nW8, 1, 32.0f);
    gemm_f16<<<gG, blk, 0, stream>>>(X3, W3, bo, 3072, 0, 1.0f, out, nullptr);
}

// Round 2
// 629.008 us; speedup vs baseline: 1.0518x; 1.0518x over previous
//
#include <hip/hip_runtime.h>

// ---------------------------------------------------------------------------
// TopK sparse attention, MI355X (gfx950)
// B=4 L=1024 E=1024 H=16 DH=64 TOPK=32
//
// Numerics (validated r3-r5, absmax 0.0176 < 0.0206): reference top-k is
// fp32-noisy; keys within btau=1.5e-5 of the rank-32/33 midpoint get
// ensemble-blended weight (32-A)/m. Selection needs logit err << btau.
// Round-6: all 4 GEMMs use fp16 3-slot split [h,l,h]x[h,h,l] (hh+lh+hl,
// residual ~2^-24), K=3072, W prescaled x32 so l-terms stay fp16-normal
// (worst-case denormal-flush err ~2.5e-6 scaled << btau). Candidate re-dot
// fp32 q,k / fp64 accum as before.
// Round-7: selection latency chains -> exact 32-bit threshold search for
// the 32nd largest (scalar chain, no LDS) + masked reduce for the 33rd +
// ballot-prefix ds_permute compaction + readlane gather.
// Round-8: THE actual bottleneck was scratch spill. launch_bounds(256,8)
// capped the unified VGPR budget at 64/lane; skey[2][16]+frags+selection
// state spilled to scratch -> 171MB WRITE_SIZE vs 16MB of real output.
// Relax to (256,4): 128 VGPR budget, no spill, ~16 waves/CU. Latency
// chains shrink (no spill-reload), HBM traffic drops to real working set.
// ---------------------------------------------------------------------------

typedef short v8s __attribute__((ext_vector_type(8)));
typedef _Float16 v8h __attribute__((ext_vector_type(8)));
typedef float v4f __attribute__((ext_vector_type(4)));

#define B_ 4
#define L_ 1024
#define E_ 1024
#define H_ 16
#define DH_ 64
#define M_ 4096   // B*L

__device__ __forceinline__ unsigned short f2bf_u(float f) {
    unsigned u = __float_as_uint(f);
    unsigned r = u + 0x7FFFu + ((u >> 16) & 1u);   // RNE
    return (unsigned short)(r >> 16);
}
__device__ __forceinline__ unsigned short f2h_u(float f) {
    _Float16 h = (_Float16)f;
    union { _Float16 h; unsigned short u; } c; c.h = h; return c.u;
}
__device__ __forceinline__ float h2f_u(unsigned short u) {
    union { _Float16 h; unsigned short u; } c; c.u = u; return (float)c.h;
}
__device__ __forceinline__ unsigned f2key(float f) {
    unsigned u = __float_as_uint(f);
    u = ((int)u < 0) ? ~u : (u | 0x80000000u);
    return u & 0xFFFFFFF0u;
}
__device__ __forceinline__ unsigned f2keyfull(float f) {   // no low-bit mask
    unsigned u = __float_as_uint(f);
    return ((int)u < 0) ? ~u : (u | 0x80000000u);
}
__device__ __forceinline__ float key2f(unsigned k) {
    unsigned u = (k & 0x80000000u) ? (k & 0x7FFFFFFFu) : ~k;
    return __uint_as_float(u);
}
__device__ __forceinline__ float rl_f(float v, int l) {    // uniform-lane broadcast
    return __uint_as_float((unsigned)__builtin_amdgcn_readlane(__float_as_int(v), l));
}
__device__ __forceinline__ int rl_i(int v, int l) {
    return __builtin_amdgcn_readlane(v, l);
}
__device__ __forceinline__ void gload_lds16(const unsigned short* g, unsigned short* l) {
    __builtin_amdgcn_global_load_lds(
        (const __attribute__((address_space(1))) void*)g,
        (__attribute__((address_space(3))) void*)l, 16, 0, 0);
}

// ---------------------------------------------------------------------------
// fp16 3-slot split, 8 elements/thread.
// A (isB=0): [h,l,h]   B (isB=1): [h,h,l]   -> GEMM computes hh+lh+hl.
// prescale: 1 for X, 32 for W (keeps l-terms fp16-normal; /32 in epilogue).
// ---------------------------------------------------------------------------
__global__ __launch_bounds__(256) void splitH_kernel(
    const float* __restrict__ x, unsigned short* __restrict__ y,
    int n8, int isB, float prescale)
{
    int i = blockIdx.x * 256 + threadIdx.x;
    if (i >= n8) return;
    float4 v0 = *(const float4*)(x + 8*(size_t)i);
    float4 v1 = *(const float4*)(x + 8*(size_t)i + 4);
    float f[8] = {v0.x, v0.y, v0.z, v0.w, v1.x, v1.y, v1.z, v1.w};
    unsigned short o[24];
#pragma unroll
    for (int c = 0; c < 8; ++c) {
        float fv = f[c] * prescale;
        unsigned short h = f2h_u(fv);
        float r = fv - h2f_u(h);
        unsigned short l = f2h_u(r);
        int b = 3*c;
        if (!isB) { o[b] = h; o[b+1] = l; o[b+2] = h; }
        else      { o[b] = h; o[b+1] = h; o[b+2] = l; }
    }
    uint4* dst = (uint4*)(y + 24*(size_t)i);
    const unsigned* ou = (const unsigned*)o;
    dst[0] = make_uint4(ou[0], ou[1], ou[2], ou[3]);
    dst[1] = make_uint4(ou[4], ou[5], ou[6], ou[7]);
    dst[2] = make_uint4(ou[8], ou[9], ou[10], ou[11]);
}

// ---------------------------------------------------------------------------
// fp16 NT GEMM, 128x64 C-tile, global_load_lds(16B) staging.
// C[m,n] = (sum_k A[m,k]*Bw[n,k]) * (1/32) + bias[n], then *scale.
// M=4096, N=1024, K2=3072. grid (16 n-tiles, 32 m-tiles) = 512 blocks (2/CU).
// 4 waves, each 32 rows x 64 cols (2x4 MFMA tiles, 16x16x32 f16).
// mode 0: outF[m*1024+n]; mode 1: outF[bh-layout]; mode 2: +outB bf16.
// ---------------------------------------------------------------------------
__global__ __launch_bounds__(256) void gemm_f16(
    const unsigned short* __restrict__ A,
    const unsigned short* __restrict__ Bw,
    const float* __restrict__ bias,
    int K2, int mode, float scale,
    float* __restrict__ outF,
    unsigned short* __restrict__ outB)
{
    __shared__ __align__(16) unsigned short As[128*64];
    __shared__ __align__(16) unsigned short Bs[64*64];
    const int t    = threadIdx.x;
    const int lane = t & 63;
    const int w    = t >> 6;
    const int quad = lane >> 4;
    const int l16  = lane & 15;
    const int n0   = blockIdx.x * 64;
    const int m0   = blockIdx.y * 128;
    const int wr   = w * 32;

    v4f acc[2][4];
#pragma unroll
    for (int i = 0; i < 2; ++i)
#pragma unroll
        for (int j = 0; j < 4; ++j) acc[i][j] = (v4f){0.f,0.f,0.f,0.f};

    const unsigned short* Ap = A  + (size_t)(m0 + (t >> 3)) * K2 + (t & 7)*8;
    const unsigned short* Bp = Bw + (size_t)(n0 + (t >> 3)) * K2 + (t & 7)*8;
    unsigned short* ldsA = &As[t*8];   // lane-linear 16B slots
    unsigned short* ldsB = &Bs[t*8];
    const size_t cstep = (size_t)32 * K2;

    for (int k0 = 0; k0 < K2; k0 += 64) {
        __syncthreads();               // readers done with LDS
#pragma unroll
        for (int c = 0; c < 4; ++c) gload_lds16(Ap + c*cstep + k0, ldsA + c*2048);
#pragma unroll
        for (int c = 0; c < 2; ++c) gload_lds16(Bp + c*cstep + k0, ldsB + c*2048);
        __syncthreads();               // vmcnt(0) drained before barrier
#pragma unroll
        for (int ks = 0; ks < 2; ++ks) {
            v8h af[2], bf[4];
#pragma unroll
            for (int mt = 0; mt < 2; ++mt)
                af[mt] = *(const v8h*)&As[(wr + mt*16 + l16)*64 + ks*32 + quad*8];
#pragma unroll
            for (int nt = 0; nt < 4; ++nt)
                bf[nt] = *(const v8h*)&Bs[(nt*16 + l16)*64 + ks*32 + quad*8];
#pragma unroll
            for (int mt = 0; mt < 2; ++mt)
#pragma unroll
                for (int nt = 0; nt < 4; ++nt)
                    acc[mt][nt] = __builtin_amdgcn_mfma_f32_16x16x32_f16(
                        af[mt], bf[nt], acc[mt][nt], 0, 0, 0);
        }
    }

#pragma unroll
    for (int nt = 0; nt < 4; ++nt) {
        int n = n0 + nt*16 + l16;
        float bb = bias[n];
#pragma unroll
        for (int mt = 0; mt < 2; ++mt) {
#pragma unroll
            for (int r = 0; r < 4; ++r) {
                int m = m0 + wr + mt*16 + quad*4 + r;
                float val = (acc[mt][nt][r] * 0.03125f + bb) * scale;
                if (mode == 0) {
                    outF[(size_t)m * 1024 + n] = val;
                } else {
                    int b = m >> 10, l = m & 1023;
                    int h = n >> 6,  d = n & 63;
                    size_t oidx = (((size_t)(b*16 + h)) * 1024 + l) * 64 + d;
                    outF[oidx] = val;
                    if (mode == 2) outB[oidx] = f2bf_u(val);
                }
            }
        }
    }
}

// ---------------------------------------------------------------------------
// Attention: one block = (b,h, 8 query rows), XCD-swizzled, grid 8192.
// Coarse S: bf16 MFMA, direct global B-frags. Counts via ballot+popcount
// (wave-uniform, no shuffle chains). Re-dot fp32 q,k / fp64 accum (2-way
// ILP). Selection: exact 32-bit bitwise threshold search for the
// 32nd-largest re-dotted logit (scalar chain, no LDS traffic), masked
// shuffle-reduce for the 33rd, ambiguity-band blended softmax
// (btau=1.5e-5), ballot-prefix ds_permute compaction, readlane-driven
// 4-way unrolled V gather.
// launch_bounds(256,4): 128 VGPR budget -> no scratch spill (at (256,8)
// the 64-reg cap spilled skey+selection state: 171MB WRITE_SIZE).
// ---------------------------------------------------------------------------
__global__ __launch_bounds__(256, 4) void attn_kernel(
    const float* __restrict__ qf,           // [64][1024][64] fp32 (scaled 1/8)
    const unsigned short* __restrict__ qb,  // bf16 of qf
    const float* __restrict__ kf,
    const unsigned short* __restrict__ kb,
    const float* __restrict__ vf,           // fp32 v, bh-layout
    float* __restrict__ ao)                 // [4096][1024]
{
    __shared__ __align__(16) float qfs[8*68];
    __shared__ __align__(16) unsigned short qbs[8*72];
    __shared__ __align__(16) float sbuf[2][8*68];
    __shared__ unsigned cand[4*64];

    const int t    = threadIdx.x;
    const int lane = t & 63;
    const int w    = t >> 6;
    const int quad = lane >> 4;
    const int l16  = lane & 15;

    // XCD swizzle: xcd = blk%8 owns bh in [xcd*8, xcd*8+8)
    const int blk = blockIdx.x;
    const int jj  = blk >> 3;               // 0..1023
    const int bh  = (blk & 7) * 8 + (jj >> 7);
    const int qt  = jj & 127;
    const int l0  = qt * 8;
    const size_t kvB = (size_t)bh * 1024;

    { // stage 8 q rows (fp32 + bf16)
        if (t < 128) {
            int row = t >> 4, c4 = (t & 15) * 4;
            *(float4*)&qfs[row*68 + c4] = *(const float4*)&qf[(kvB + l0 + row)*64 + c4];
        }
        if (t < 64) {
            int r2 = t >> 3, cc = t & 7;
            *(uint4*)&qbs[r2*72 + cc*8] = *(const uint4*)&qb[(kvB + l0 + r2)*64 + cc*8];
        }
    }
    __syncthreads();
    v8s afr[2];
#pragma unroll
    for (int ks = 0; ks < 2; ++ks)
        afr[ks] = *(const v8s*)&qbs[(l16 & 7)*72 + ks*32 + quad*8];

    unsigned skey[2][16];

    // coarse pass: wave w covers k-rows w*16+l16 within each 64-row k-tile
    const unsigned short* kbase = kb + (kvB + w*16 + l16) * 64 + quad*8;
    v8s nb0 = *(const v8s*)(kbase);
    v8s nb1 = *(const v8s*)(kbase + 32);
#pragma unroll
    for (int kt = 0; kt < 16; ++kt) {
        v8s b0 = nb0, b1 = nb1;
        if (kt < 15) {
            nb0 = *(const v8s*)(kbase + (kt+1)*4096);
            nb1 = *(const v8s*)(kbase + (kt+1)*4096 + 32);
        }
        v4f acc = (v4f){0.f,0.f,0.f,0.f};
        acc = __builtin_amdgcn_mfma_f32_16x16x32_bf16(afr[0], b0, acc, 0, 0, 0);
        acc = __builtin_amdgcn_mfma_f32_16x16x32_bf16(afr[1], b1, acc, 0, 0, 0);
        if (quad < 2) {            // rows 8..15 duplicate 0..7
#pragma unroll
            for (int r = 0; r < 4; ++r)
                sbuf[kt & 1][(quad*4 + r)*68 + w*16 + l16] = acc[r];
        }
        __syncthreads();
#pragma unroll
        for (int rr = 0; rr < 2; ++rr) {
            float sv = sbuf[kt & 1][(w*2 + rr)*68 + lane];
            unsigned u = __float_as_uint(sv);
            u = ((int)u < 0) ? ~u : (u | 0x80000000u);
            skey[rr][kt] = (u & 0xFFFFFFF0u) | (unsigned)kt;  // idx in low bits
        }
    }

#pragma unroll
    for (int rr = 0; rr < 2; ++rr) {
        const int qrow = w*2 + rr;

        // --- row max (shuffle reduce, once) ---
        unsigned kmax = 0;
#pragma unroll
        for (int kt = 0; kt < 16; ++kt) kmax = max(kmax, skey[rr][kt]);
#pragma unroll
        for (int off = 32; off; off >>= 1)
            kmax = max(kmax, (unsigned)__shfl_xor((int)kmax, off));
        float fm = key2f(kmax);

        // --- threshold search, counts via ballot+popcount (wave-uniform) ---
        unsigned tau = 0; bool ok = false;
        if (fm > 0.f) {
            float lof = 0.28f * fm, hif = 0.88f * fm;
            for (int it = 0; it < 12; ++it) {
                float midf = 0.5f * (lof + hif);
                unsigned tk = f2key(midf);
                int c = 0;
#pragma unroll
                for (int kt = 0; kt < 16; ++kt)
                    c += (int)__popcll(__ballot(skey[rr][kt] >= tk));
                tau = tk;
                if (c <= 64 && c >= 36) { ok = true; break; }
                if (c > 64) lof = midf; else hif = midf;
            }
        }
        if (!ok) { // full-range u32 fallback (guaranteed window)
            unsigned lo = 0u, hi = 0xFFFFFFFFu;
            for (int it = 0; ; ++it) {
                unsigned mid = lo + ((hi - lo) >> 1);
                int c = 0;
#pragma unroll
                for (int kt = 0; kt < 16; ++kt)
                    c += (int)__popcll(__ballot(skey[rr][kt] >= mid));
                tau = mid;
                if (it >= 33 || (c <= 64 && c >= 36)) break;
                if (c > 64) lo = mid + 1; else hi = mid - 1;
            }
        }

        // --- compact candidate indices ---
        int base = 0;
#pragma unroll
        for (int kt = 0; kt < 16; ++kt) {
            bool f = skey[rr][kt] >= tau;
            unsigned long long mk = __ballot(f);
            if (f) {
                int pos = base + (int)__popcll(mk & ((1ull << lane) - 1ull));
                if (pos < 64) cand[w*64 + pos] = (unsigned)(kt*64 + lane);
            }
            base += (int)__popcll(mk);
        }
        int cnum = base > 64 ? 64 : base;

        // --- re-dot: fp32 q,k, fp64 accumulate, 2-way ILP ---
        int cj = 0x3FFFFFFF;
        float ef = -INFINITY;
        if (lane < cnum) {
            cj = (int)cand[w*64 + lane];
            const float* kr = kf + (kvB + cj) * 64;
            double s0 = 0.0, s1 = 0.0;
#pragma unroll
            for (int d4 = 0; d4 < 16; d4 += 2) {
                float4 qa = *(const float4*)&qfs[qrow*68 + d4*4];
                float4 ka = *(const float4*)&kr[d4*4];
                float4 qb2 = *(const float4*)&qfs[qrow*68 + d4*4 + 4];
                float4 kb2 = *(const float4*)&kr[d4*4 + 4];
                s0 += (double)qa.x * ka.x; s0 += (double)qa.y * ka.y;
                s0 += (double)qa.z * ka.z; s0 += (double)qa.w * ka.w;
                s1 += (double)qb2.x * kb2.x; s1 += (double)qb2.y * kb2.y;
                s1 += (double)qb2.z * kb2.z; s1 += (double)qb2.w * kb2.w;
            }
            ef = (float)(s0 + s1);
        }

        // --- exact 32nd-largest via bitwise threshold search (no LDS) ---
        // T = max{ t : count(uf >= t) >= 32 } == sortable key of v32.
        const unsigned uf = f2keyfull(ef);
        unsigned T = 0u;
#pragma unroll
        for (int b = 31; b >= 0; --b) {
            unsigned cndt = T | (1u << b);
            int c = (int)__popcll(__ballot(uf >= cndt));
            if (c >= 32) T = cndt;            // c uniform -> s_cselect
        }
        float e31 = key2f(T);                  // 32nd largest (exact float)
        int c_ge = (int)__popcll(__ballot(uf >= T));

        // --- 33rd largest + row max (two interleaved reduce chains) ---
        float mx = ef;
        float tm = (uf < T) ? ef : -INFINITY;
#pragma unroll
        for (int off = 32; off; off >>= 1) {
            mx = fmaxf(mx, __shfl_xor(mx, off));
            tm = fmaxf(tm, __shfl_xor(tm, off));
        }
        float e32v = (c_ge >= 33) ? e31 : tm;  // duplicates at rank 32/33

        // --- ambiguity-band blended softmax (validated, btau=1.5e-5) ---
        float cmid = 0.5f * (e31 + e32v);
        const float btau = 1.5e-5f;
        bool certain = (ef > cmid + btau);
        bool band    = (fabsf(ef - cmid) <= btau);
        int A = (int)__popcll(__ballot(certain));
        int m = (int)__popcll(__ballot(band));
        float wgt = band ? ((float)(32 - A) / (float)m) : (certain ? 1.f : 0.f);

        float p = wgt * __expf(ef - mx);
        float Z = p;
#pragma unroll
        for (int off = 32; off; off >>= 1) Z += __shfl_xor(Z, off);

        // --- compact wgt>0 lanes to a prefix (full-exec permutation push) ---
        bool sel = (wgt > 0.f);
        unsigned long long mk = __ballot(sel);
        int nnz = (int)__popcll(mk);
        unsigned long long lt = (1ull << lane) - 1ull;
        int pos = sel ? (int)__popcll(mk & lt)
                      : nnz + (int)__popcll(~mk & lt);
        float pc = __uint_as_float((unsigned)__builtin_amdgcn_ds_permute(
                       pos << 2, __float_as_int(p)));
        int   cc = __builtin_amdgcn_ds_permute(pos << 2, cj);

        // --- gather V: readlane broadcasts, 4 independent chains ---
        const float* vbase = vf + kvB * 64 + lane;
        float o0 = 0.f, o1 = 0.f, o2 = 0.f, o3 = 0.f;
        int tt = 0;
        for (; tt + 3 < nnz; tt += 4) {
            float pa = rl_f(pc, tt),   pb = rl_f(pc, tt+1);
            float pcc = rl_f(pc, tt+2), pd = rl_f(pc, tt+3);
            int ia = rl_i(cc, tt),   ib = rl_i(cc, tt+1);
            int ic = rl_i(cc, tt+2), id = rl_i(cc, tt+3);
            o0 += pa  * vbase[ia * 64];
            o1 += pb  * vbase[ib * 64];
            o2 += pcc * vbase[ic * 64];
            o3 += pd  * vbase[id * 64];
        }
        for (; tt < nnz; ++tt) {
            float pt  = rl_f(pc, tt);
            int   it2 = rl_i(cc, tt);
            o0 += pt * vbase[it2 * 64];
        }
        float o = (o0 + o1) + (o2 + o3);
        int lq = l0 + qrow;
        ao[((size_t)(bh >> 4) * 1024 + lq) * 1024 + (bh & 15) * 64 + lane] = o / Z;
    }
}

// ---------------------------------------------------------------------------
extern "C" void kernel_launch(void* const* d_in, const int* in_sizes, int n_in,
                              void* d_out, int out_size, void* d_ws, size_t ws_size,
                              hipStream_t stream)
{
    const float* Q  = (const float*)d_in[0];
    const float* K  = (const float*)d_in[1];
    const float* V  = (const float*)d_in[2];
    const float* Wq = (const float*)d_in[3];
    const float* bq = (const float*)d_in[4];
    const float* Wk = (const float*)d_in[5];
    const float* bk = (const float*)d_in[6];
    const float* Wv = (const float*)d_in[7];
    const float* bv = (const float*)d_in[8];
    const float* Wo = (const float*)d_in[9];
    const float* bo = (const float*)d_in[10];
    float* out = (float*)d_out;

    // workspace layout (bytes)
    const size_t oX3 = 0;            // 4096*3072*2 = 25165824
    const size_t oW3 = 25165824;     // 1024*3072*2 = 6291456
    const size_t oQF = 31457280;     // 16777216
    const size_t oKF = 48234496;     // 16777216
    const size_t oVF = 65011712;     // 16777216
    const size_t oQB = 81788928;     // 8388608
    const size_t oKB = 90177536;     // 8388608
    const size_t oAO = 98566144;     // 16777216 -> end 115343360
    if (ws_size < 115343360) return;

    char* ws = (char*)d_ws;
    unsigned short* X3 = (unsigned short*)(ws + oX3);
    unsigned short* W3 = (unsigned short*)(ws + oW3);
    float* qf = (float*)(ws + oQF);
    float* kf = (float*)(ws + oKF);
    float* vf = (float*)(ws + oVF);
    unsigned short* qb = (unsigned short*)(ws + oQB);
    unsigned short* kb = (unsigned short*)(ws + oKB);
    float* ao = (float*)(ws + oAO);

    const int nX8 = M_ * E_ / 8;     // 524288
    const int nW8 = E_ * E_ / 8;     // 131072
    dim3 blk(256);
    dim3 gG(16, 32);                 // (n-tiles 64, m-tiles 128)
    dim3 gX(nX8 / 256), gW(nW8 / 256);

    // Q path (fold 1/sqrt(DH)=0.125 into stored q)
    splitH_kernel<<<gX, blk, 0, stream>>>(Q, X3, nX8, 0, 1.0f);
    splitH_kernel<<<gW, blk, 0, stream>>>(Wq, W3, nW8, 1, 32.0f);
    gemm_f16<<<gG, blk, 0, stream>>>(X3, W3, bq, 3072, 2, 0.125f, qf, qb);
    // K path
    splitH_kernel<<<gX, blk, 0, stream>>>(K, X3, nX8, 0, 1.0f);
    splitH_kernel<<<gW, blk, 0, stream>>>(Wk, W3, nW8, 1, 32.0f);
    gemm_f16<<<gG, blk, 0, stream>>>(X3, W3, bk, 3072, 2, 1.0f, kf, kb);
    // V path
    splitH_kernel<<<gX, blk, 0, stream>>>(V, X3, nX8, 0, 1.0f);
    splitH_kernel<<<gW, blk, 0, stream>>>(Wv, W3, nW8, 1, 32.0f);
    gemm_f16<<<gG, blk, 0, stream>>>(X3, W3, bv, 3072, 1, 1.0f, vf, nullptr);
    // attention (8 rows/block)
    attn_kernel<<<dim3(8192), blk, 0, stream>>>(qf, qb, kf, kb, vf, ao);
    // output projection
    splitH_kernel<<<gX, blk, 0, stream>>>(ao, X3, nX8, 0, 1.0f);
    splitH_kernel<<<gW, blk, 0, stream>>>(Wo, W3, nW8, 1, 32.0f);
    gemm_f16<<<gG, blk, 0, stream>>>(X3, W3, bo, 3072, 0, 1.0f, out, nullptr);
}